// Round 16
// baseline (285.720 us; speedup 1.0000x reference)
//
#include <hip/hip_runtime.h>
#include <hip/hip_bf16.h>

#define NN 50000
#define NE 400000
#define AVG_LOG_F 2.1972245773362196f
#define EPSV 1e-5f

typedef __hip_bfloat16 bf16;
typedef __attribute__((ext_vector_type(8))) short short8v;
typedef __attribute__((ext_vector_type(4))) float f32x4;
typedef __attribute__((ext_vector_type(2))) _Float16 h2v;

struct __attribute__((aligned(4))) u12 { unsigned x, y, z; };
union P12 { u12 u; h2v h[3]; };

__device__ __forceinline__ bf16  f2b(float v){ return __float2bfloat16(v); }
__device__ __forceinline__ short f2s(float v){
  bf16 b = __float2bfloat16(v);
  short s; __builtin_memcpy(&s, &b, 2); return s;
}
__device__ __forceinline__ short f2h(float v){
  _Float16 h = (_Float16)v;
  short s; __builtin_memcpy(&s, &h, 2); return s;
}

// ================= fused pre-chain =================
// blocks [0,12500): h0 ; [12500,12891): zero deg/cursor ; [12891,13403): ctab ;
// [13403,14363): wtk ; [14363,14587): wtpre896
#define PB_H0  12500
#define PB_Z   12891
#define PB_CT  13403
#define PB_WK  14363
#define PB_END 14587

__global__ __launch_bounds__(256) void k_pre(const int* __restrict__ x,
                                             const float* __restrict__ aemb,
                                             const float* __restrict__ bemb,
                                             const float* __restrict__ preW,
                                             const float* __restrict__ preb,
                                             const float* __restrict__ postW,
                                             const float* __restrict__ postb,
                                             bf16* __restrict__ h0b,
                                             int* __restrict__ deg, int* __restrict__ cursor,
                                             char* __restrict__ CTp,
                                             bf16* __restrict__ WtKf,
                                             bf16* __restrict__ Wtp,
                                             float* __restrict__ bias896){
  __shared__ float et[64];
  const int b = blockIdx.x, t = threadIdx.x;
  if (b < PB_H0){
    int idx = b * 256 + t;                       // < 3.2M exactly
    int n = idx >> 6, d = idx & 63;
    float acc = 0.f;
    #pragma unroll
    for (int c = 0; c < 9; ++c){
      int a = x[n * 9 + c];
      acc += aemb[(c * 64 + a) * 64 + d];
    }
    h0b[idx] = f2b(acc);
  } else if (b < PB_Z){
    int idx = (b - PB_H0) * 256 + t;
    if (idx < NN) deg[idx] = 0;
    else if (idx < 2 * NN) cursor[idx - NN] = 0;
  } else if (b < PB_CT){
    int cb = b - PB_Z;                           // 0..511
    if (t < 64){
      int a0 = cb & 7, a1 = (cb >> 3) & 7, a2 = (cb >> 6) & 7;
      et[t] = bemb[a0 * 64 + t] + bemb[(8 + a1) * 64 + t] + bemb[(16 + a2) * 64 + t];
    }
    __syncthreads();
    char* base = CTp + (size_t)cb * 1024;
    for (int w = t; w < 320; w += 256){
      int l = w >> 6, dd = w & 63;
      float acc = 0.f;
      const float* W = preW + (l * 192 + 128) * 64;
      for (int k = 0; k < 64; ++k) acc += et[k] * W[k * 64 + dd];
      *(short*)(base + dd * 12 + l * 2) = f2h(acc);
    }
    if (t < 64) *(short*)(base + t * 12 + 10) = 0;   // l=5 pad slot
  } else if (b < PB_WK){
    int idx = (b - PB_CT) * 256 + t;             // < 245760 exactly
    int s   = idx / 6144;
    int rem = idx % 6144;
    int gw  = rem / 512;
    int lane = (rem % 512) / 8;
    int j   = idx & 7;
    int g = gw >> 2, w4 = gw & 3;
    int kp = s * 32 + (lane >> 4) * 8 + j;
    int l = kp >> 8, kl = kp & 255;
    int c = w4 * 16 + (lane & 15);
    WtKf[idx] = f2b(postW[((size_t)l * 832 + g * 256 + kl) * 64 + c]);
  } else {
    int idx = (b - PB_WK) * 256 + t;             // < 57344 exactly
    {
      int gc = idx >> 6, k = idx & 63;
      float v;
      if (gc < 320){
        int l = gc >> 6, c = gc & 63;
        v = preW[(size_t)(l * 192 + k) * 64 + c];
      } else if (gc < 832){
        int q = gc - 320, d = q >> 3, l = q & 7;
        v = (l < 5) ? preW[(size_t)(l * 192 + 64 + k) * 64 + d] : 0.f;
      } else {
        int c = gc - 832;
        float a = 0.f;
        #pragma unroll
        for (int l = 0; l < 5; ++l) a += postW[(size_t)(l * 832 + 768 + k) * 64 + c];
        v = a + ((k == c) ? 1.f : 0.f);
      }
      Wtp[idx] = f2b(v);
    }
    if (idx < 896){
      float bb;
      if (idx < 320)      bb = preb[(idx >> 6) * 64 + (idx & 63)];
      else if (idx < 832) bb = 0.f;
      else {
        float a = 0.f;
        #pragma unroll
        for (int l = 0; l < 5; ++l) a += postb[l * 64 + (idx - 832)];
        bb = a;
      }
      bias896[idx] = bb;
    }
  }
}

// ---------- degree histogram + bond code ----------
__global__ void k_deg_code(const int* __restrict__ ei, const int* __restrict__ ea,
                           int* __restrict__ deg, int* __restrict__ code){
  int e = blockIdx.x * 256 + threadIdx.x;
  if (e >= NE) return;
  int dst = ei[NE + e];
  atomicAdd(&deg[dst], 1);
  code[e] = ea[e * 3] + 8 * ea[e * 3 + 1] + 64 * ea[e * 3 + 2];
}

// ---------- exclusive scan of deg -> rowptr ----------
__global__ void k_scan1(const int* __restrict__ deg, int* __restrict__ rowptr,
                        int* __restrict__ part){
  __shared__ int s[256];
  int t = threadIdx.x, i = blockIdx.x * 256 + t;
  int v = (i < NN) ? deg[i] : 0;
  s[t] = v; __syncthreads();
  for (int off = 1; off < 256; off <<= 1){
    int xv = (t >= off) ? s[t - off] : 0;
    __syncthreads();
    s[t] += xv;
    __syncthreads();
  }
  if (i < NN) rowptr[i] = s[t] - v;
  if (t == 255) part[blockIdx.x] = s[255];
}

__global__ void k_scan2(int* __restrict__ part, int nblk){
  __shared__ int s[256];
  int t = threadIdx.x;
  int v = (t < nblk) ? part[t] : 0;
  s[t] = v; __syncthreads();
  for (int off = 1; off < 256; off <<= 1){
    int xv = (t >= off) ? s[t - off] : 0;
    __syncthreads();
    s[t] += xv;
    __syncthreads();
  }
  if (t < nblk) part[t] = s[t] - v;
}

__global__ void k_scan3(int* __restrict__ rowptr, const int* __restrict__ part,
                        const int* __restrict__ deg, float* __restrict__ amp,
                        float* __restrict__ att){
  int i = blockIdx.x * 256 + threadIdx.x;
  if (i < NN){
    rowptr[i] += part[blockIdx.x];
    int d = deg[i];
    float ld = logf((float)max(d, 1) + 1.0f);
    amp[i] = ld / AVG_LOG_F;
    att[i] = AVG_LOG_F / ld;
  }
  if (i == 0) rowptr[NN] = NE;
}

// ---------- scatter edges into CSR order, pre-multiplied byte offsets ----------
// sedge.x = src*2048 + 1024 (B12 plane base in ABU), sedge.y = code*1024 (CTp base)
__global__ void k_scatter(const int* __restrict__ ei, const int* __restrict__ code,
                          const int* __restrict__ rowptr, int* __restrict__ cursor,
                          int2* __restrict__ sedge){
  int e = blockIdx.x * 256 + threadIdx.x;
  if (e >= NE) return;
  int dst = ei[NE + e];
  int pos = rowptr[dst] + atomicAdd(&cursor[dst], 1);
  int2 v; v.x = ei[e] * 2048 + 1024; v.y = code[e] * 1024;
  sedge[pos] = v;
}

// ---------- ABU(fp16)+out = h0b[N,64] @ Wtp896[64,896] via MFMA ----------
// ABU[n] (2048B): [0,640) A-part l*128+c*2; [1024,1792) B12 dd*12+l*2 (l<6, l5=0)
__global__ __launch_bounds__(256) void k_ab_mfma(const bf16* __restrict__ h0b,
                                                 const bf16* __restrict__ Wtp,
                                                 const float* __restrict__ bias896,
                                                 char* __restrict__ ABU,
                                                 float* __restrict__ out){
  __shared__ bf16 As[128][72];
  __shared__ bf16 Bs[128][72];
  const int t = threadIdx.x;
  const int n0 = blockIdx.x * 128;
  const int gc0 = blockIdx.y * 128;
  const int lane = t & 63, wid = t >> 6;
  const int rw = wid * 32;
  const short* H  = (const short*)h0b;
  const short* Wp = (const short*)Wtp;

  #pragma unroll
  for (int i = 0; i < 4; ++i){
    int idx = t + i * 256;
    int r = idx >> 3, ko = (idx & 7) * 8;
    int n = n0 + r;
    short8v v = short8v{0,0,0,0,0,0,0,0};
    if (n < NN) v = *(const short8v*)(H + (size_t)n * 64 + ko);
    *(short8v*)&As[r][ko] = v;
  }
  #pragma unroll
  for (int i = 0; i < 4; ++i){
    int idx = t + i * 256;
    int cc = idx >> 3, ko = (idx & 7) * 8;
    *(short8v*)&Bs[cc][ko] = *(const short8v*)(Wp + (size_t)(gc0 + cc) * 64 + ko);
  }
  __syncthreads();

  f32x4 acc[2][8] = {};
  #pragma unroll
  for (int kk = 0; kk < 2; ++kk){
    short8v af0 = *(const short8v*)&As[rw + (lane & 15)][kk * 32 + (lane >> 4) * 8];
    short8v af1 = *(const short8v*)&As[rw + 16 + (lane & 15)][kk * 32 + (lane >> 4) * 8];
    #pragma unroll
    for (int j = 0; j < 8; ++j){
      short8v bfj = *(const short8v*)&Bs[j * 16 + (lane & 15)][kk * 32 + (lane >> 4) * 8];
      acc[0][j] = __builtin_amdgcn_mfma_f32_16x16x32_bf16(af0, bfj, acc[0][j], 0, 0, 0);
      acc[1][j] = __builtin_amdgcn_mfma_f32_16x16x32_bf16(af1, bfj, acc[1][j], 0, 0, 0);
    }
  }

  #pragma unroll
  for (int i = 0; i < 2; ++i){
    #pragma unroll
    for (int r = 0; r < 4; ++r){
      int n = n0 + rw + i * 16 + (lane >> 4) * 4 + r;
      if (n >= NN) continue;
      char* nb = ABU + (size_t)n * 2048;
      #pragma unroll
      for (int j = 0; j < 8; ++j){
        int gc = gc0 + j * 16 + (lane & 15);
        float v = acc[i][j][r] + bias896[gc];
        if (gc < 320){
          *(short*)(nb + gc * 2) = f2h(v);
        } else if (gc < 832){
          int q = gc - 320, dd = q >> 3, l = q & 7;
          if (l < 6) *(short*)(nb + 1024 + dd * 12 + l * 2) = f2h(v);  // l==5 -> v==0
        } else {
          out[(size_t)n * 64 + (gc - 832)] = v;
        }
      }
    }
  }
}

// ---------- fused gather + posttrans GEMM (4-wave tail, 12B payload) ----------
__global__ __launch_bounds__(1024, 2) void k_gather(const char* __restrict__ ABU,
                                                    const char* __restrict__ CTp,
                                                    const int* __restrict__ rowptr,
                                                    const int2* __restrict__ sedge,
                                                    const bf16* __restrict__ WtKf,
                                                    const float* __restrict__ amp,
                                                    const float* __restrict__ att,
                                                    float* __restrict__ out){
  __shared__ __align__(16) short ag[16][1288];
  const int t = threadIdx.x, lane = t & 63, wid = t >> 6;   // wid 0..15
  const int n = blockIdx.x * 16 + wid;          // NN % 16 == 0, always valid

  int r0 = rowptr[n], r1 = rowptr[n + 1];
  float s[5]  = {0.f, 0.f, 0.f, 0.f, 0.f};
  float sq[5] = {0.f, 0.f, 0.f, 0.f, 0.f};
  const _Float16 FLO = (_Float16)(-65504.f);
  const _Float16 FHI = (_Float16)( 65504.f);
  h2v mx01 = h2v{FLO, FLO}, mx23 = h2v{FLO, FLO}, mx45 = h2v{FLO, FLO};
  h2v mn01 = h2v{FHI, FHI}, mn23 = h2v{FHI, FHI}, mn45 = h2v{FHI, FHI};

  const int l12 = lane * 12;

  for (int j = r0; j < r1; j += 4){
    int rem = r1 - j;
    int2 e0 = sedge[j];
    int2 e1 = (rem > 1) ? sedge[j + 1] : e0;
    int2 e2 = (rem > 2) ? sedge[j + 2] : e0;
    int2 e3 = (rem > 3) ? sedge[j + 3] : e0;
    P12 a0, a1, a2, a3, c0, c1, c2, c3;
    a0.u = *(const u12*)(ABU + e0.x + l12);
    c0.u = *(const u12*)(CTp + e0.y + l12);
    a1.u = *(const u12*)(ABU + e1.x + l12);
    c1.u = *(const u12*)(CTp + e1.y + l12);
    a2.u = *(const u12*)(ABU + e2.x + l12);
    c2.u = *(const u12*)(CTp + e2.y + l12);
    a3.u = *(const u12*)(ABU + e3.x + l12);
    c3.u = *(const u12*)(CTp + e3.y + l12);

    #define EDGE_ACC(A, C) {                                        \
      h2v t01 = A.h[0] + C.h[0];                                    \
      h2v t23 = A.h[1] + C.h[1];                                    \
      h2v t45 = A.h[2] + C.h[2];                                    \
      mx01 = __builtin_elementwise_max(mx01, t01);                  \
      mx23 = __builtin_elementwise_max(mx23, t23);                  \
      mx45 = __builtin_elementwise_max(mx45, t45);                  \
      mn01 = __builtin_elementwise_min(mn01, t01);                  \
      mn23 = __builtin_elementwise_min(mn23, t23);                  \
      mn45 = __builtin_elementwise_min(mn45, t45);                  \
      float f0 = (float)t01[0], f1 = (float)t01[1];                 \
      float f2 = (float)t23[0], f3 = (float)t23[1];                 \
      float f4 = (float)t45[0];                                     \
      s[0] += f0; sq[0] = fmaf(f0, f0, sq[0]);                      \
      s[1] += f1; sq[1] = fmaf(f1, f1, sq[1]);                      \
      s[2] += f2; sq[2] = fmaf(f2, f2, sq[2]);                      \
      s[3] += f3; sq[3] = fmaf(f3, f3, sq[3]);                      \
      s[4] += f4; sq[4] = fmaf(f4, f4, sq[4]);                      \
    }
    EDGE_ACC(a0, c0);
    if (rem > 1) EDGE_ACC(a1, c1);
    if (rem > 2) EDGE_ACC(a2, c2);
    if (rem > 3) EDGE_ACC(a3, c3);
    #undef EDGE_ACC
  }

  float mx[5] = {(float)mx01[0], (float)mx01[1], (float)mx23[0], (float)mx23[1], (float)mx45[0]};
  float mn[5] = {(float)mn01[0], (float)mn01[1], (float)mn23[0], (float)mn23[1], (float)mn45[0]};

  int d = r1 - r0;
  float degc = (float)((d > 0) ? d : 1);
  const char* nb = ABU + (size_t)n * 2048;
  #pragma unroll
  for (int l = 0; l < 5; ++l){
    _Float16 Kh; __builtin_memcpy(&Kh, nb + l * 128 + lane * 2, 2);
    float K = (float)Kh;                                  // includes pre_b
    float mean = ((float)d * K + s[l]) / degc;
    float MX = (d > 0) ? (K + mx[l]) : 0.f;
    float MN = (d > 0) ? (K + mn[l]) : 0.f;
    float mu = s[l] / degc;
    float var = fmaxf(sq[l] / degc - mu * mu, 0.f);
    float sd = sqrtf(var + EPSV);
    ag[wid][l * 256 + lane]       = f2s(mean);
    ag[wid][l * 256 + 64 + lane]  = f2s(MX);
    ag[wid][l * 256 + 128 + lane] = f2s(MN);
    ag[wid][l * 256 + 192 + lane] = f2s(sd);
  }
  __syncthreads();

  if (wid >= 4) return;   // no further barriers: legal early exit

  // ---- GEMM tail: waves 0-3, col-slice = wid; A-frags from ag LDS ----
  const char* pb = (const char*)WtKf + wid * 1024 + lane * 16;
  const short* agrow = &ag[lane & 15][(lane >> 4) * 8];
  f32x4 acc[3] = {};
  short8v Bx[3], By[3];

  #define LOADB(dst, sidx) { \
    _Pragma("unroll") for (int g = 0; g < 3; ++g) \
      dst[g] = *(const short8v*)(pb + (size_t)(sidx) * 12288 + g * 4096); }
  #define MFMA3(af, B) { \
    _Pragma("unroll") for (int g = 0; g < 3; ++g) \
      acc[g] = __builtin_amdgcn_mfma_f32_16x16x32_bf16(af, B[g], acc[g], 0, 0, 0); }

  LOADB(Bx, 0);
  for (int k = 0; k < 19; ++k){
    LOADB(By, 2 * k + 1);
    short8v af0 = *(const short8v*)(agrow + (2 * k) * 32);
    MFMA3(af0, Bx);
    LOADB(Bx, 2 * k + 2);
    short8v af1 = *(const short8v*)(agrow + (2 * k + 1) * 32);
    MFMA3(af1, By);
  }
  LOADB(By, 39);
  {
    short8v af0 = *(const short8v*)(agrow + 38 * 32);
    MFMA3(af0, Bx);
    short8v af1 = *(const short8v*)(agrow + 39 * 32);
    MFMA3(af1, By);
  }
  #undef LOADB
  #undef MFMA3

  // epilogue: out += U + amp*V + att*W  (C/D: col=lane&15, row=(lane>>4)*4+reg)
  #pragma unroll
  for (int r = 0; r < 4; ++r){
    int row = (lane >> 4) * 4 + r;
    int nn = blockIdx.x * 16 + row;
    float am = amp[nn], at = att[nn];
    int c = wid * 16 + (lane & 15);
    out[(size_t)nn * 64 + c] += acc[0][r] + am * acc[1][r] + at * acc[2][r];
  }
}

extern "C" void kernel_launch(void* const* d_in, const int* in_sizes, int n_in,
                              void* d_out, int out_size, void* d_ws, size_t ws_size,
                              hipStream_t stream){
  const int*   x     = (const int*)d_in[0];
  const int*   ei    = (const int*)d_in[1];
  const int*   ea    = (const int*)d_in[2];
  const float* aemb  = (const float*)d_in[3];
  const float* bemb  = (const float*)d_in[4];
  const float* preW  = (const float*)d_in[5];
  const float* preb  = (const float*)d_in[6];
  const float* postW = (const float*)d_in[7];
  const float* postb = (const float*)d_in[8];
  float* out = (float*)d_out;

  char* p = (char*)d_ws;
  auto alloc = [&](size_t bytes) -> char* {
    char* r = p;
    p += (bytes + 255) & ~(size_t)255;
    return r;
  };
  bf16*      h0b     = (bf16*)     alloc((size_t)NN * 64 * 2);
  char*      ABU     = (char*)     alloc((size_t)NN * 2048);
  int*       deg     = (int*)      alloc((size_t)NN * 4);
  int*       rowptr  = (int*)      alloc((size_t)(NN + 1) * 4);
  int*       cursor  = (int*)      alloc((size_t)NN * 4);
  float*     amp     = (float*)    alloc((size_t)NN * 4);
  float*     att     = (float*)    alloc((size_t)NN * 4);
  int*       code    = (int*)      alloc((size_t)NE * 4);
  int2*      sedge   = (int2*)     alloc((size_t)NE * 8);
  char*      CTp     = (char*)     alloc((size_t)512 * 1024);
  int*       part    = (int*)      alloc((size_t)256 * 4);
  bf16*      WtKf    = (bf16*)     alloc((size_t)40 * 12 * 64 * 8 * 2);
  bf16*      Wtp     = (bf16*)     alloc((size_t)896 * 64 * 2);
  float*     bias896 = (float*)    alloc((size_t)896 * 4);
  if ((size_t)(p - (char*)d_ws) > ws_size) return;

  k_pre<<<dim3(PB_END), 256, 0, stream>>>(x, aemb, bemb, preW, preb, postW, postb,
                                          h0b, deg, cursor, CTp, WtKf, Wtp, bias896);
  k_deg_code<<<dim3((NE + 255) / 256), 256, 0, stream>>>(ei, ea, deg, code);
  int nblk = (NN + 255) / 256;
  k_scan1<<<dim3(nblk), 256, 0, stream>>>(deg, rowptr, part);
  k_scan2<<<dim3(1), 256, 0, stream>>>(part, nblk);
  k_scan3<<<dim3(nblk), 256, 0, stream>>>(rowptr, part, deg, amp, att);
  k_scatter<<<dim3((NE + 255) / 256), 256, 0, stream>>>(ei, code, rowptr, cursor, sedge);
  k_ab_mfma<<<dim3((NN + 127) / 128, 7), 256, 0, stream>>>(h0b, Wtp, bias896, ABU, out);
  k_gather<<<dim3(NN / 16), 1024, 0, stream>>>(ABU, (const char*)CTp, rowptr, sedge,
                                               WtKf, amp, att, out);
}